// Round 12
// baseline (225.189 us; speedup 1.0000x reference)
//
#include <hip/hip_runtime.h>
#include <hip/hip_cooperative_groups.h>
#include <hip/hip_bf16.h>
#include <math.h>

namespace cg = cooperative_groups;

// Problem constants (fixed by setup_inputs)
#define EDGES   32768
#define NPTS    32768
#define IMGH    256
#define L0      32768
#define L1      16384
#define L2      8192
#define L3      4096
#define S0      (L1 + 64)    // Y0 row stride (padded)

// Batched weight-chunk staging from pre-transposed Wt: 1536 float4, 6/thread.
__device__ __forceinline__ void stage_ws(float ws[96][64],
                                         const float* __restrict__ Wsrc, int tid)
{
    const float4* src = (const float4*)Wsrc;
    float4 rw[6];
#pragma unroll
    for (int k = 0; k < 6; ++k) rw[k] = src[k * 256 + tid];
    float4* dst = (float4*)&ws[0][0];
#pragma unroll
    for (int k = 0; k < 6; ++k) dst[k * 256 + tid] = rw[k];
}

// 64x64 k=3 stride-2 conv compute on a staged half (convA).
__device__ __forceinline__ void conv_half(float acc[16],
                                          const float xs[64][130],
                                          const float ws[96][64],
                                          int ibase, int jl2, int o0)
{
#pragma unroll 4
    for (int ii = 0; ii < 32; ++ii) {
        int i = ibase + ii;
        float x0 = xs[i][jl2], x1 = xs[i][jl2 + 1], x2 = xs[i][jl2 + 2];
        const float4* w0 = (const float4*)&ws[ii*3 + 0][o0];
        const float4* w1 = (const float4*)&ws[ii*3 + 1][o0];
        const float4* w2 = (const float4*)&ws[ii*3 + 2][o0];
#pragma unroll
        for (int q = 0; q < 4; ++q) {
            float4 a = w0[q], b = w1[q], c = w2[q];
            acc[q*4+0] = fmaf(a.x, x0, fmaf(b.x, x1, fmaf(c.x, x2, acc[q*4+0])));
            acc[q*4+1] = fmaf(a.y, x0, fmaf(b.y, x1, fmaf(c.y, x2, acc[q*4+1])));
            acc[q*4+2] = fmaf(a.z, x0, fmaf(b.z, x1, fmaf(c.z, x2, acc[q*4+2])));
            acc[q*4+3] = fmaf(a.w, x0, fmaf(b.w, x1, fmaf(c.w, x2, acc[q*4+3])));
        }
    }
}

// ---------------------------------------------------------------------------
// Cooperative mega-kernel: 256 blocks x 256 threads, 4 grid.sync phases.
// ---------------------------------------------------------------------------
__global__ __launch_bounds__(256) void mega_k(
    const float* __restrict__ corners,
    const float* __restrict__ img,
    const float* __restrict__ W0, const float* __restrict__ W1,
    const float* __restrict__ W2,
    const float* __restrict__ b0v, const float* __restrict__ b1v,
    const float* __restrict__ b2v,
    const float* __restrict__ Wf, const float* __restrict__ bf,
    const float* __restrict__ Wp, const float* __restrict__ bp,
    double* __restrict__ el2loc, double* __restrict__ partial,
    float2* __restrict__ pts, int* __restrict__ ridx,
    float* __restrict__ Wt, float* __restrict__ imgT,
    float* __restrict__ Y0, float* __restrict__ pmax,
    float* __restrict__ out)
{
    cg::grid_group grid = cg::this_grid();
    __shared__ union {
        struct { double sc[256]; } p0s;                                     //  2 KB
        struct { float tt[64][68]; } p0t;                                   // 17.4 KB
        struct { double sb[128]; } p1;                                      //  1 KB
        struct { float xs[64][130]; float ws[96][64]; } a;                  // 57856 B
        struct { float xs0[32][76]; float t1[64][34]; float ws[96][64];
                 float cm[64]; float ft[64]; } bc;                          // ~44 KB
    } sm;
    int b = blockIdx.x, tid = threadIdx.x;

    // ================= PHASE 0: scan | weights | image transpose ==========
    if (b < 128) {
        int e  = (b << 8) + tid;
        int en = (e + 1) & (EDGES - 1);
        double dx = (double)corners[2*en]   - (double)corners[2*e];
        double dy = (double)corners[2*en+1] - (double)corners[2*e+1];
        sm.p0s.sc[tid] = sqrt(dx*dx + dy*dy);
        __syncthreads();
        for (int o = 1; o < 256; o <<= 1) {            // Hillis-Steele inclusive
            double v = (tid >= o) ? sm.p0s.sc[tid - o] : 0.0;
            __syncthreads();
            sm.p0s.sc[tid] += v;
            __syncthreads();
        }
        el2loc[e] = sm.p0s.sc[tid];
        if (tid == 255) partial[b] = sm.p0s.sc[255];
    } else if (b < 146) {
        int wb = b - 128;
#pragma unroll
        for (int k = 0; k < 8; ++k) {
            int idx = wb*2048 + k*256 + tid;           // < 36864 exactly
            if (idx < 36864) {
                int l   = idx / 12288;
                int rem = idx - l * 12288;
                int row = rem >> 6, o = rem & 63;
                int i   = row / 3,  kk = row - i * 3;
                const float* W = (l == 0) ? W0 : ((l == 1) ? W1 : W2);
                Wt[idx] = W[o*192 + i*3 + kk];
            }
        }
    }
    __syncthreads();
    // all 256 blocks: 4 transpose tiles each (vectorized)
    for (int it = 0; it < 4; ++it) {
        int tb   = (b << 2) + it;
        int pix0 = tb << 6;
        const float4* img4 = (const float4*)img;
        __syncthreads();
#pragma unroll
        for (int k = 0; k < 4; ++k) {
            int idx = k*256 + tid;
            if (idx < 992) {                           // 62 ch x 16 float4
                int c = idx >> 4, p4 = idx & 15;
                float4 v = img4[c*16384 + (pix0 >> 2) + p4];
                sm.p0t.tt[p4*4 + 0][c] = v.x;
                sm.p0t.tt[p4*4 + 1][c] = v.y;
                sm.p0t.tt[p4*4 + 2][c] = v.z;
                sm.p0t.tt[p4*4 + 3][c] = v.w;
            }
        }
        __syncthreads();
        float4* imgT4 = (float4*)imgT;
#pragma unroll
        for (int k = 0; k < 4; ++k) {
            int idx = k*256 + tid;                     // < 1024
            int p = idx >> 4, c4 = idx & 15;
            if (c4 < 15) {
                float4 v = *(const float4*)&sm.p0t.tt[p][c4*4];
                imgT4[((size_t)(pix0 + p) << 4) + c4] = v;
            } else {                                   // ch 60,61 (62/63 unused)
                float2 v = make_float2(sm.p0t.tt[p][60], sm.p0t.tt[p][61]);
                *(float2*)(imgT + ((size_t)(pix0 + p) << 6) + 60) = v;
            }
        }
    }
    grid.sync();

    // ================= PHASE 1: point search (128 pts / block) =============
    {
        if (tid < 128) sm.p1.sb[tid] = partial[tid];
        __syncthreads();
        for (int o = 1; o < 128; o <<= 1) {
            double v = 0.0;
            if (tid < 128 && tid >= o) v = sm.p1.sb[tid - o];
            __syncthreads();
            if (tid < 128) sm.p1.sb[tid] += v;
            __syncthreads();
        }
        if (tid < 128) {
            int p = (b << 7) + tid;
            double S   = sm.p1.sb[127];
            double off = (double)p * (S * (1.0 / (double)NPTS));
            int clo = 0, chi = 127;
            while (clo < chi) { int cm = (clo + chi) >> 1;
                                if (sm.p1.sb[cm] > off) chi = cm; else clo = cm + 1; }
            double base = clo ? sm.p1.sb[clo - 1] : 0.0;
            int lo = clo << 8, hi = lo + 255;
            while (lo < hi) { int mid = (lo + hi) >> 1;
                              if (el2loc[mid] + base > off) hi = mid; else lo = mid + 1; }
            int e = lo;
            double e1 = (e == 0) ? 0.0
                      : el2loc[e-1] + (((e-1) >= 256) ? sm.p1.sb[((e-1) >> 8) - 1] : 0.0);
            float sxf = corners[2*e], syf = corners[2*e+1];
            int en = (e + 1) & (EDGES - 1);
            double dx = (double)corners[2*en]   - (double)sxf;
            double dy = (double)corners[2*en+1] - (double)syf;
            double len = sqrt(dx*dx + dy*dy);
            double tp  = (off - e1) / fmax(len, 0.0001);
            double px  = (double)sxf + tp * dx;
            double py  = (double)syf + tp * dy;
            int r0 = (int)rint(px * (double)IMGH); r0 = r0 < 0 ? 0 : (r0 > IMGH-1 ? IMGH-1 : r0);
            int r1 = (int)rint(py * (double)IMGH); r1 = r1 < 0 ? 0 : (r1 > IMGH-1 ? IMGH-1 : r1);
            pts[p]  = make_float2((float)px, (float)py);
            ridx[p] = (r0 << 8) | r1;
        }
    }
    grid.sync();

    // ================= PHASE 2: convA (gather + conv0) -> Y0 ===============
    {
        int j0  = b << 6;
        int in0 = (j0 << 1) - 1;
        stage_ws(sm.a.ws, Wt, tid);                    // W0 chunk 0
        if (tid < 130) {
            int g = in0 + tid;
            if (g < 0)   g = 1;                        // reflect left
            if (g >= L0) g = 2*L0 - 2 - g;             // halo guard
            float2 pxy = pts[g];
            int    rid = ridx[g];
            const float4* row4 = (const float4*)(imgT + ((size_t)rid << 6));
            float4 rv[15];
#pragma unroll
            for (int c4 = 0; c4 < 15; ++c4) rv[c4] = row4[c4];
            float c60 = ((const float*)row4)[60], c61 = ((const float*)row4)[61];
#pragma unroll
            for (int c4 = 0; c4 < 15; ++c4) {
                sm.a.xs[c4*4 + 0][tid] = rv[c4].x;
                sm.a.xs[c4*4 + 1][tid] = rv[c4].y;
                sm.a.xs[c4*4 + 2][tid] = rv[c4].z;
                sm.a.xs[c4*4 + 3][tid] = rv[c4].w;
            }
            sm.a.xs[60][tid] = c60;
            sm.a.xs[61][tid] = c61;
            sm.a.xs[62][tid] = pxy.x;
            sm.a.xs[63][tid] = pxy.y;
        }
        __syncthreads();

        int lane = tid & 63;
        int o0   = (tid >> 6) << 4;
        float acc[16];
#pragma unroll
        for (int m = 0; m < 16; ++m) acc[m] = b0v[o0 + m];
        int jl2 = lane << 1;

        conv_half(acc, sm.a.xs, sm.a.ws, 0, jl2, o0);
        __syncthreads();
        stage_ws(sm.a.ws, Wt + 96*64, tid);            // W0 chunk 1
        __syncthreads();
        conv_half(acc, sm.a.xs, sm.a.ws, 32, jl2, o0);

        int j = j0 + lane;
#pragma unroll
        for (int m = 0; m < 16; ++m)
            Y0[(o0 + m) * S0 + j] = fmaxf(acc[m], 0.f);
    }
    grid.sync();

    // ====== PHASE 3: convBC (16 outputs/block, 256 blocks) -> pmax =========
    {
        int gbase = 64*b - 4;
        int s  = tid & 63;                             // conv1 slot (33 used)
        int o0 = (tid >> 6) << 4;
        int j1 = 32*b - 1 + s;
        int jr = (j1 < 0) ? -j1 : (j1 > L2-1 ? L2-1 : j1);
        int col0 = 2*jr - 64*b + 3;
        col0 = col0 > 69 ? 69 : col0;                  // clamp inactive lanes in-tile

        {   // stage Y0 half-0 (in-ch 0..31) + W1 chunk0
            float r[9];
#pragma unroll
            for (int k = 0; k < 9; ++k) {
                int idx = k*256 + tid;                 // 2304 = 9*256 exactly
                int c   = idx / 72, col = idx - 72*c;
                int g   = gbase + col;
                if (g < 0)   g = -g;
                if (g >= L1) g = 2*L1 - 2 - g;
                r[k] = Y0[c * S0 + g];
            }
            stage_ws(sm.bc.ws, Wt + 12288, tid);
#pragma unroll
            for (int k = 0; k < 9; ++k) {
                int idx = k*256 + tid;
                int c   = idx / 72, col = idx - 72*c;
                sm.bc.xs0[c][col] = r[k];
            }
        }
        __syncthreads();

        float acc1[16];
#pragma unroll
        for (int m = 0; m < 16; ++m) acc1[m] = b1v[o0 + m];
#pragma unroll 4
        for (int ii = 0; ii < 32; ++ii) {
            float x0 = sm.bc.xs0[ii][col0], x1 = sm.bc.xs0[ii][col0+1], x2 = sm.bc.xs0[ii][col0+2];
            const float4* w0 = (const float4*)&sm.bc.ws[ii*3 + 0][o0];
            const float4* w1 = (const float4*)&sm.bc.ws[ii*3 + 1][o0];
            const float4* w2 = (const float4*)&sm.bc.ws[ii*3 + 2][o0];
#pragma unroll
            for (int q = 0; q < 4; ++q) {
                float4 a = w0[q], bw = w1[q], c = w2[q];
                acc1[q*4+0] = fmaf(a.x, x0, fmaf(bw.x, x1, fmaf(c.x, x2, acc1[q*4+0])));
                acc1[q*4+1] = fmaf(a.y, x0, fmaf(bw.y, x1, fmaf(c.y, x2, acc1[q*4+1])));
                acc1[q*4+2] = fmaf(a.z, x0, fmaf(bw.z, x1, fmaf(c.z, x2, acc1[q*4+2])));
                acc1[q*4+3] = fmaf(a.w, x0, fmaf(bw.w, x1, fmaf(c.w, x2, acc1[q*4+3])));
            }
        }
        __syncthreads();
        {   // stage Y0 half-1 (in-ch 32..63) + W1 chunk1
            float r[9];
#pragma unroll
            for (int k = 0; k < 9; ++k) {
                int idx = k*256 + tid;
                int c   = idx / 72, col = idx - 72*c;
                int g   = gbase + col;
                if (g < 0)   g = -g;
                if (g >= L1) g = 2*L1 - 2 - g;
                r[k] = Y0[(32 + c) * S0 + g];
            }
            stage_ws(sm.bc.ws, Wt + 12288 + 96*64, tid);
#pragma unroll
            for (int k = 0; k < 9; ++k) {
                int idx = k*256 + tid;
                int c   = idx / 72, col = idx - 72*c;
                sm.bc.xs0[c][col] = r[k];
            }
        }
        __syncthreads();
#pragma unroll 4
        for (int ii = 0; ii < 32; ++ii) {
            float x0 = sm.bc.xs0[ii][col0], x1 = sm.bc.xs0[ii][col0+1], x2 = sm.bc.xs0[ii][col0+2];
            const float4* w0 = (const float4*)&sm.bc.ws[ii*3 + 0][o0];
            const float4* w1 = (const float4*)&sm.bc.ws[ii*3 + 1][o0];
            const float4* w2 = (const float4*)&sm.bc.ws[ii*3 + 2][o0];
#pragma unroll
            for (int q = 0; q < 4; ++q) {
                float4 a = w0[q], bw = w1[q], c = w2[q];
                acc1[q*4+0] = fmaf(a.x, x0, fmaf(bw.x, x1, fmaf(c.x, x2, acc1[q*4+0])));
                acc1[q*4+1] = fmaf(a.y, x0, fmaf(bw.y, x1, fmaf(c.y, x2, acc1[q*4+1])));
                acc1[q*4+2] = fmaf(a.z, x0, fmaf(bw.z, x1, fmaf(c.z, x2, acc1[q*4+2])));
                acc1[q*4+3] = fmaf(a.w, x0, fmaf(bw.w, x1, fmaf(c.w, x2, acc1[q*4+3])));
            }
        }
        __syncthreads();
        if (s < 33) {
#pragma unroll
            for (int m = 0; m < 16; ++m) sm.bc.t1[o0 + m][s] = fmaxf(acc1[m], 0.f);
        }
        __syncthreads();

        // conv2: thread -> (pos p 0..15, 4-ch group)
        int p  = tid & 15;
        int oc = (tid >> 4) << 2;
        float acc2[4];
#pragma unroll
        for (int q = 0; q < 4; ++q) acc2[q] = b2v[oc + q];

        stage_ws(sm.bc.ws, Wt + 24576, tid);           // W2 chunk0
        __syncthreads();
#pragma unroll 4
        for (int ii = 0; ii < 32; ++ii) {
            float x0 = sm.bc.t1[ii][2*p + 0], x1 = sm.bc.t1[ii][2*p + 1], x2 = sm.bc.t1[ii][2*p + 2];
            float4 a = *(const float4*)&sm.bc.ws[ii*3 + 0][oc];
            float4 bw = *(const float4*)&sm.bc.ws[ii*3 + 1][oc];
            float4 c = *(const float4*)&sm.bc.ws[ii*3 + 2][oc];
            acc2[0] = fmaf(a.x, x0, fmaf(bw.x, x1, fmaf(c.x, x2, acc2[0])));
            acc2[1] = fmaf(a.y, x0, fmaf(bw.y, x1, fmaf(c.y, x2, acc2[1])));
            acc2[2] = fmaf(a.z, x0, fmaf(bw.z, x1, fmaf(c.z, x2, acc2[2])));
            acc2[3] = fmaf(a.w, x0, fmaf(bw.w, x1, fmaf(c.w, x2, acc2[3])));
        }
        __syncthreads();
        stage_ws(sm.bc.ws, Wt + 24576 + 96*64, tid);   // W2 chunk1
        __syncthreads();
#pragma unroll 4
        for (int ii = 0; ii < 32; ++ii) {
            float x0 = sm.bc.t1[32+ii][2*p + 0], x1 = sm.bc.t1[32+ii][2*p + 1], x2 = sm.bc.t1[32+ii][2*p + 2];
            float4 a = *(const float4*)&sm.bc.ws[ii*3 + 0][oc];
            float4 bw = *(const float4*)&sm.bc.ws[ii*3 + 1][oc];
            float4 c = *(const float4*)&sm.bc.ws[ii*3 + 2][oc];
            acc2[0] = fmaf(a.x, x0, fmaf(bw.x, x1, fmaf(c.x, x2, acc2[0])));
            acc2[1] = fmaf(a.y, x0, fmaf(bw.y, x1, fmaf(c.y, x2, acc2[1])));
            acc2[2] = fmaf(a.z, x0, fmaf(bw.z, x1, fmaf(c.z, x2, acc2[2])));
            acc2[3] = fmaf(a.w, x0, fmaf(bw.w, x1, fmaf(c.w, x2, acc2[3])));
        }

        // per-block channel max over 16 positions (all valid: 256*16 = 4096)
#pragma unroll
        for (int q = 0; q < 4; ++q) {
            float v = fmaxf(acc2[q], 0.f);
#pragma unroll
            for (int off = 1; off < 16; off <<= 1)
                v = fmaxf(v, __shfl_xor(v, off));
            if (p == 0) pmax[b * 64 + oc + q] = v;
        }
    }
    grid.sync();

    // ================= PHASE 4: channel max + FCs (block 0) ================
    if (b == 0) {
        if (tid < 64) {
            float m = 0.f;
            for (int q = 0; q < 256; ++q) m = fmaxf(m, pmax[q * 64 + tid]);
            sm.bc.cm[tid] = m;
        }
        __syncthreads();
        if (tid < 64) {
            float sfc = bf[tid];
#pragma unroll
            for (int c = 0; c < 64; ++c) sfc = fmaf(Wf[tid*64 + c], sm.bc.cm[c], sfc);
            float f = fmaxf(sfc, 0.f);
            sm.bc.ft[tid] = f;
            out[tid] = f;
        }
        __syncthreads();
        if (tid == 0) {
            float z = bp[0];
#pragma unroll
            for (int c = 0; c < 64; ++c) z = fmaf(Wp[c], sm.bc.ft[c], z);
            out[64] = 1.f / (1.f + expf(-z));
        }
    }
}

// ---------------------------------------------------------------------------
extern "C" void kernel_launch(void* const* d_in, const int* in_sizes, int n_in,
                              void* d_out, int out_size, void* d_ws, size_t ws_size,
                              hipStream_t stream)
{
    const float* image   = (const float*)d_in[0];
    const float* corners = (const float*)d_in[1];
    const float* W0      = (const float*)d_in[2];
    const float* b0      = (const float*)d_in[3];
    const float* W1      = (const float*)d_in[4];
    const float* b1      = (const float*)d_in[5];
    const float* W2      = (const float*)d_in[6];
    const float* b2      = (const float*)d_in[7];
    const float* Wf      = (const float*)d_in[8];
    const float* bf      = (const float*)d_in[9];
    const float* Wp      = (const float*)d_in[10];
    const float* bp      = (const float*)d_in[11];
    float* out = (float*)d_out;

    // workspace layout (256B-aligned), ~21.9 MB used
    char* w = (char*)d_ws;
    double* el2loc  = (double*)(w);                  //   262144 B
    double* partial = (double*)(w + 262144);         //     1024 B
    float2* pts     = (float2*)(w + 263168);         //   262144 B
    int*    ridx    = (int*)   (w + 525312);         //   131072 B
    float*  pmax    = (float*) (w + 656384);         //    65536 B
    float*  Wt      = (float*) (w + 721920);         //   147456 B
    float*  imgT    = (float*) (w + 869376);         // 16777216 B
    float*  Y0      = (float*) (w + 17646592);       //  4210688 B -> 21857280

    void* args[] = {
        (void*)&corners, (void*)&image,
        (void*)&W0, (void*)&W1, (void*)&W2,
        (void*)&b0, (void*)&b1, (void*)&b2,
        (void*)&Wf, (void*)&bf, (void*)&Wp, (void*)&bp,
        (void*)&el2loc, (void*)&partial, (void*)&pts, (void*)&ridx,
        (void*)&Wt, (void*)&imgT, (void*)&Y0, (void*)&pmax, (void*)&out
    };
    hipLaunchCooperativeKernel((void*)mega_k, dim3(256), dim3(256),
                               args, 0, stream);
}

// Round 13
// 57.893 us; speedup vs baseline: 3.8897x; 3.8897x over previous
//
#include <hip/hip_runtime.h>
#include <hip/hip_bf16.h>
#include <math.h>

// Problem constants (fixed by setup_inputs)
#define EDGES   32768
#define NPTS    32768
#define IMGH    256
#define L0      32768
#define L1      16384
#define L2      8192
#define L3      4096
#define S0      (L1 + 64)    // Y0 row stride (padded)
#define NBC     133          // convBC blocks (31 outputs each)

// prep4 block ranges: [0,128) scan | [128,146) weights | [146,1170) transpose
#define P4_SCAN 128
#define P4_W    18
#define P4_T    1024
#define P4_GRID (P4_SCAN + P4_W + P4_T)   // 1170

// Batched weight-chunk staging from pre-transposed Wt: 1536 float4, 6/thread.
__device__ __forceinline__ void stage_ws(float ws[96][64],
                                         const float* __restrict__ Wsrc, int tid)
{
    const float4* src = (const float4*)Wsrc;
    float4 rw[6];
#pragma unroll
    for (int k = 0; k < 6; ++k) rw[k] = src[k * 256 + tid];
    float4* dst = (float4*)&ws[0][0];
#pragma unroll
    for (int k = 0; k < 6; ++k) dst[k * 256 + tid] = rw[k];
}

// 64x64 k=3 stride-2 conv compute on a staged half.
__device__ __forceinline__ void conv_half(float acc[16],
                                          const float xs[64][130],
                                          const float ws[96][64],
                                          int ibase, int jl2, int o0)
{
#pragma unroll 4
    for (int ii = 0; ii < 32; ++ii) {
        int i = ibase + ii;
        float x0 = xs[i][jl2], x1 = xs[i][jl2 + 1], x2 = xs[i][jl2 + 2];
        const float4* w0 = (const float4*)&ws[ii*3 + 0][o0];
        const float4* w1 = (const float4*)&ws[ii*3 + 1][o0];
        const float4* w2 = (const float4*)&ws[ii*3 + 2][o0];
#pragma unroll
        for (int q = 0; q < 4; ++q) {
            float4 a = w0[q], b = w1[q], c = w2[q];
            acc[q*4+0] = fmaf(a.x, x0, fmaf(b.x, x1, fmaf(c.x, x2, acc[q*4+0])));
            acc[q*4+1] = fmaf(a.y, x0, fmaf(b.y, x1, fmaf(c.y, x2, acc[q*4+1])));
            acc[q*4+2] = fmaf(a.z, x0, fmaf(b.z, x1, fmaf(c.z, x2, acc[q*4+2])));
            acc[q*4+3] = fmaf(a.w, x0, fmaf(b.w, x1, fmaf(c.w, x2, acc[q*4+3])));
        }
    }
}

// ---------------------------------------------------------------------------
// Kernel 1 (prep4): scan | weight transpose | vectorized image transpose.
// Three independent block ranges, no cross-block dependencies.
// ---------------------------------------------------------------------------
__global__ __launch_bounds__(256) void prep4_k(const float* __restrict__ corners,
                                               const float* __restrict__ W0,
                                               const float* __restrict__ W1,
                                               const float* __restrict__ W2,
                                               const float* __restrict__ img,
                                               double* __restrict__ el2loc,
                                               double* __restrict__ partial,
                                               float*  __restrict__ Wt,
                                               float*  __restrict__ imgT)
{
    __shared__ union {
        double sc[256];        // scan
        float  tt[64][68];     // transpose tile [pixel][channel]
    } sm;
    int b = blockIdx.x, t = threadIdx.x;

    if (b < P4_SCAN) {
        int e  = (b << 8) + t;
        int en = (e + 1) & (EDGES - 1);
        double dx = (double)corners[2*en]   - (double)corners[2*e];
        double dy = (double)corners[2*en+1] - (double)corners[2*e+1];
        sm.sc[t] = sqrt(dx*dx + dy*dy);
        __syncthreads();
        for (int o = 1; o < 256; o <<= 1) {        // Hillis-Steele inclusive
            double v = (t >= o) ? sm.sc[t - o] : 0.0;
            __syncthreads();
            sm.sc[t] += v;
            __syncthreads();
        }
        el2loc[e] = sm.sc[t];
        if (t == 255) partial[b] = sm.sc[255];
    } else if (b < P4_SCAN + P4_W) {
        int wb = b - P4_SCAN;
#pragma unroll
        for (int k = 0; k < 8; ++k) {
            int idx = wb*2048 + k*256 + t;         // < 36864 exactly
            int l   = idx / 12288;
            int rem = idx - l * 12288;
            int row = rem >> 6, o = rem & 63;
            int i   = row / 3,  kk = row - i * 3;
            const float* W = (l == 0) ? W0 : ((l == 1) ? W1 : W2);
            Wt[idx] = W[o*192 + i*3 + kk];
        }
    } else {
        int tb   = b - (P4_SCAN + P4_W);
        int pix0 = tb << 6;                        // 64 pixels/block
        const float4* img4 = (const float4*)img;
#pragma unroll
        for (int k = 0; k < 4; ++k) {
            int idx = k*256 + t;
            if (idx < 992) {                       // 62 ch x 16 float4
                int c = idx >> 4, p4 = idx & 15;
                float4 v = img4[c*16384 + (pix0 >> 2) + p4];
                sm.tt[p4*4 + 0][c] = v.x;
                sm.tt[p4*4 + 1][c] = v.y;
                sm.tt[p4*4 + 2][c] = v.z;
                sm.tt[p4*4 + 3][c] = v.w;
            }
        }
        __syncthreads();
        float4* imgT4 = (float4*)imgT;
#pragma unroll
        for (int k = 0; k < 4; ++k) {
            int idx = k*256 + t;                   // < 1024
            int p = idx >> 4, c4 = idx & 15;
            if (c4 < 15) {
                float4 v = *(const float4*)&sm.tt[p][c4*4];
                imgT4[((size_t)(pix0 + p) << 4) + c4] = v;
            } else {                               // channels 60,61 (62/63 unused)
                float2 v = make_float2(sm.tt[p][60], sm.tt[p][61]);
                *(float2*)(imgT + ((size_t)(pix0 + p) << 6) + 60) = v;
            }
        }
    }
}

// ---------------------------------------------------------------------------
// Kernel 2 (convA4): partial-scan + two-level point search + gather + conv0.
// ---------------------------------------------------------------------------
__global__ __launch_bounds__(256) void convA4_k(const float* __restrict__ corners,
                                                const double* __restrict__ el2loc,
                                                const double* __restrict__ partial,
                                                const float* __restrict__ imgT,
                                                const float* __restrict__ Wt,
                                                const float* __restrict__ b0v,
                                                float* __restrict__ Y0)
{
    __shared__ float  xs[64][130];   // 33280 B
    __shared__ float  ws[96][64];    // 24576 B
    __shared__ double sb[128];       //  1024 B
    int tid = threadIdx.x;
    int b   = blockIdx.x;
    int j0  = b << 6;
    int in0 = (j0 << 1) - 1;

    // in-block inclusive scan of the 128 chunk partials
    if (tid < 128) sb[tid] = partial[tid];
    __syncthreads();
#pragma unroll
    for (int o = 1; o < 128; o <<= 1) {
        double v = 0.0;
        if (tid < 128 && tid >= o) v = sb[tid - o];
        __syncthreads();
        if (tid < 128) sb[tid] += v;
        __syncthreads();
    }

    stage_ws(ws, Wt, tid);                         // W0 chunk 0

    if (tid < 130) {
        int g = in0 + tid;
        if (g < 0)   g = 1;                        // reflect left
        if (g >= L0) g = 2*L0 - 2 - g;             // halo guard
        double S   = sb[127];
        double off = (double)g * (S * (1.0 / (double)NPTS));
        int clo = 0, chi = 127;
        while (clo < chi) { int cm = (clo + chi) >> 1;
                            if (sb[cm] > off) chi = cm; else clo = cm + 1; }
        double base = clo ? sb[clo - 1] : 0.0;
        int lo = clo << 8, hi = lo + 255;
        while (lo < hi) { int mid = (lo + hi) >> 1;
                          if (el2loc[mid] + base > off) hi = mid; else lo = mid + 1; }
        int e = lo;
        double e1 = (e == 0) ? 0.0
                  : el2loc[e-1] + (((e-1) >= 256) ? sb[((e-1) >> 8) - 1] : 0.0);
        float sxf = corners[2*e], syf = corners[2*e+1];
        int en = (e + 1) & (EDGES - 1);
        double dx = (double)corners[2*en]   - (double)sxf;
        double dy = (double)corners[2*en+1] - (double)syf;
        double len = sqrt(dx*dx + dy*dy);
        double tp  = (off - e1) / fmax(len, 0.0001);
        double px  = (double)sxf + tp * dx;
        double py  = (double)syf + tp * dy;
        int r0 = (int)rint(px * (double)IMGH); r0 = r0 < 0 ? 0 : (r0 > IMGH-1 ? IMGH-1 : r0);
        int r1 = (int)rint(py * (double)IMGH); r1 = r1 < 0 ? 0 : (r1 > IMGH-1 ? IMGH-1 : r1);
        const float4* row4 = (const float4*)(imgT + ((size_t)((r0 << 8) | r1) << 6));
        float4 rv[15];
#pragma unroll
        for (int c4 = 0; c4 < 15; ++c4) rv[c4] = row4[c4];
        float c60 = ((const float*)row4)[60], c61 = ((const float*)row4)[61];
#pragma unroll
        for (int c4 = 0; c4 < 15; ++c4) {
            xs[c4*4 + 0][tid] = rv[c4].x;
            xs[c4*4 + 1][tid] = rv[c4].y;
            xs[c4*4 + 2][tid] = rv[c4].z;
            xs[c4*4 + 3][tid] = rv[c4].w;
        }
        xs[60][tid] = c60;
        xs[61][tid] = c61;
        xs[62][tid] = (float)px;
        xs[63][tid] = (float)py;
    }
    __syncthreads();

    int lane = tid & 63;
    int o0   = (tid >> 6) << 4;
    float acc[16];
#pragma unroll
    for (int m = 0; m < 16; ++m) acc[m] = b0v[o0 + m];
    int jl2 = lane << 1;

    conv_half(acc, xs, ws, 0, jl2, o0);
    __syncthreads();
    stage_ws(ws, Wt + 96*64, tid);                 // W0 chunk 1
    __syncthreads();
    conv_half(acc, xs, ws, 32, jl2, o0);

    int j = j0 + lane;
#pragma unroll
    for (int m = 0; m < 16; ++m)
        Y0[(o0 + m) * S0 + j] = fmaxf(acc[m], 0.f);
}

// ---------------------------------------------------------------------------
// Kernel 3 (convBC): conv1 + conv2 fused; Y1 never materialized.
// ---------------------------------------------------------------------------
__global__ __launch_bounds__(256) void convBC_k(const float* __restrict__ Y0,
                                                const float* __restrict__ Wt1,
                                                const float* __restrict__ b1,
                                                const float* __restrict__ Wt2,
                                                const float* __restrict__ b2,
                                                float* __restrict__ pmax)
{
    __shared__ float xs0[32][132];   // 16896 B
    __shared__ float t1[64][63];     // 16128 B
    __shared__ float ws[96][64];     // 24576 B
    int tid = threadIdx.x;
    int b   = blockIdx.x;
    int gbase = 124*b - 3;

    int s  = tid & 63;
    int o0 = (tid >> 6) << 4;
    int j1 = 62*b - 1 + s;
    int jr = (j1 < 0) ? -j1 : (j1 > L2-1 ? L2-1 : j1);
    int col0 = 2*jr - 124*b + 2;

    {   // stage Y0 half-0 (in-ch 0..31) + W1 chunk0
        float r[16];
#pragma unroll
        for (int k = 0; k < 16; ++k) {
            int idx = k*256 + tid;
            int c   = idx >> 7, col = idx & 127;
            int g   = gbase + col;
            if (g < 0)   g = -g;
            if (g >= L1) g = 2*L1 - 2 - g;
            r[k] = Y0[c * S0 + g];
        }
        stage_ws(ws, Wt1, tid);
#pragma unroll
        for (int k = 0; k < 16; ++k) {
            int idx = k*256 + tid;
            xs0[idx >> 7][idx & 127] = r[k];
        }
    }
    __syncthreads();

    float acc1[16];
#pragma unroll
    for (int m = 0; m < 16; ++m) acc1[m] = b1[o0 + m];
#pragma unroll 4
    for (int ii = 0; ii < 32; ++ii) {
        float x0 = xs0[ii][col0], x1 = xs0[ii][col0+1], x2 = xs0[ii][col0+2];
        const float4* w0 = (const float4*)&ws[ii*3 + 0][o0];
        const float4* w1 = (const float4*)&ws[ii*3 + 1][o0];
        const float4* w2 = (const float4*)&ws[ii*3 + 2][o0];
#pragma unroll
        for (int q = 0; q < 4; ++q) {
            float4 a = w0[q], bb = w1[q], c = w2[q];
            acc1[q*4+0] = fmaf(a.x, x0, fmaf(bb.x, x1, fmaf(c.x, x2, acc1[q*4+0])));
            acc1[q*4+1] = fmaf(a.y, x0, fmaf(bb.y, x1, fmaf(c.y, x2, acc1[q*4+1])));
            acc1[q*4+2] = fmaf(a.z, x0, fmaf(bb.z, x1, fmaf(c.z, x2, acc1[q*4+2])));
            acc1[q*4+3] = fmaf(a.w, x0, fmaf(bb.w, x1, fmaf(c.w, x2, acc1[q*4+3])));
        }
    }
    __syncthreads();
    {   // stage Y0 half-1 (in-ch 32..63) + W1 chunk1
        float r[16];
#pragma unroll
        for (int k = 0; k < 16; ++k) {
            int idx = k*256 + tid;
            int c   = idx >> 7, col = idx & 127;
            int g   = gbase + col;
            if (g < 0)   g = -g;
            if (g >= L1) g = 2*L1 - 2 - g;
            r[k] = Y0[(32 + c) * S0 + g];
        }
        stage_ws(ws, Wt1 + 96*64, tid);
#pragma unroll
        for (int k = 0; k < 16; ++k) {
            int idx = k*256 + tid;
            xs0[idx >> 7][idx & 127] = r[k];
        }
    }
    __syncthreads();
#pragma unroll 4
    for (int ii = 0; ii < 32; ++ii) {
        float x0 = xs0[ii][col0], x1 = xs0[ii][col0+1], x2 = xs0[ii][col0+2];
        const float4* w0 = (const float4*)&ws[ii*3 + 0][o0];
        const float4* w1 = (const float4*)&ws[ii*3 + 1][o0];
        const float4* w2 = (const float4*)&ws[ii*3 + 2][o0];
#pragma unroll
        for (int q = 0; q < 4; ++q) {
            float4 a = w0[q], bb = w1[q], c = w2[q];
            acc1[q*4+0] = fmaf(a.x, x0, fmaf(bb.x, x1, fmaf(c.x, x2, acc1[q*4+0])));
            acc1[q*4+1] = fmaf(a.y, x0, fmaf(bb.y, x1, fmaf(c.y, x2, acc1[q*4+1])));
            acc1[q*4+2] = fmaf(a.z, x0, fmaf(bb.z, x1, fmaf(c.z, x2, acc1[q*4+2])));
            acc1[q*4+3] = fmaf(a.w, x0, fmaf(bb.w, x1, fmaf(c.w, x2, acc1[q*4+3])));
        }
    }
    __syncthreads();
    if (s < 63) {
#pragma unroll
        for (int m = 0; m < 16; ++m) t1[o0 + m][s] = fmaxf(acc1[m], 0.f);
    }
    __syncthreads();

    // conv2: thread -> (pos p, 8-ch group)
    int p  = tid & 31;
    int oc = (tid >> 5) << 3;
    float acc2[8];
#pragma unroll
    for (int q = 0; q < 8; ++q) acc2[q] = b2[oc + q];

    stage_ws(ws, Wt2, tid);              // W2 chunk0
    __syncthreads();
#pragma unroll 4
    for (int ii = 0; ii < 32; ++ii) {
        float x0 = t1[ii][2*p + 0], x1 = t1[ii][2*p + 1], x2 = t1[ii][2*p + 2];
        const float4* w0 = (const float4*)&ws[ii*3 + 0][oc];
        const float4* w1 = (const float4*)&ws[ii*3 + 1][oc];
        const float4* w2 = (const float4*)&ws[ii*3 + 2][oc];
#pragma unroll
        for (int q4 = 0; q4 < 2; ++q4) {
            float4 a = w0[q4], bb = w1[q4], c = w2[q4];
            acc2[q4*4+0] = fmaf(a.x, x0, fmaf(bb.x, x1, fmaf(c.x, x2, acc2[q4*4+0])));
            acc2[q4*4+1] = fmaf(a.y, x0, fmaf(bb.y, x1, fmaf(c.y, x2, acc2[q4*4+1])));
            acc2[q4*4+2] = fmaf(a.z, x0, fmaf(bb.z, x1, fmaf(c.z, x2, acc2[q4*4+2])));
            acc2[q4*4+3] = fmaf(a.w, x0, fmaf(bb.w, x1, fmaf(c.w, x2, acc2[q4*4+3])));
        }
    }
    __syncthreads();
    stage_ws(ws, Wt2 + 96*64, tid);      // W2 chunk1
    __syncthreads();
#pragma unroll 4
    for (int ii = 0; ii < 32; ++ii) {
        float x0 = t1[32+ii][2*p + 0], x1 = t1[32+ii][2*p + 1], x2 = t1[32+ii][2*p + 2];
        const float4* w0 = (const float4*)&ws[ii*3 + 0][oc];
        const float4* w1 = (const float4*)&ws[ii*3 + 1][oc];
        const float4* w2 = (const float4*)&ws[ii*3 + 2][oc];
#pragma unroll
        for (int q4 = 0; q4 < 2; ++q4) {
            float4 a = w0[q4], bb = w1[q4], c = w2[q4];
            acc2[q4*4+0] = fmaf(a.x, x0, fmaf(bb.x, x1, fmaf(c.x, x2, acc2[q4*4+0])));
            acc2[q4*4+1] = fmaf(a.y, x0, fmaf(bb.y, x1, fmaf(c.y, x2, acc2[q4*4+1])));
            acc2[q4*4+2] = fmaf(a.z, x0, fmaf(bb.z, x1, fmaf(c.z, x2, acc2[q4*4+2])));
            acc2[q4*4+3] = fmaf(a.w, x0, fmaf(bb.w, x1, fmaf(c.w, x2, acc2[q4*4+3])));
        }
    }

    bool valid = (p < 31) && (31*b + p < L3);
#pragma unroll
    for (int q = 0; q < 8; ++q) {
        float v = valid ? fmaxf(acc2[q], 0.f) : 0.f;
#pragma unroll
        for (int off = 1; off < 32; off <<= 1)
            v = fmaxf(v, __shfl_xor(v, off));
        if (p == 0) pmax[b * 64 + oc + q] = v;
    }
}

// ---------------------------------------------------------------------------
// Kernel 4: channel max over NBC block-partials (4-way parallel), FCs, sigmoid.
// ---------------------------------------------------------------------------
__global__ __launch_bounds__(256) void fc_k(const float* __restrict__ pmax,
                                            const float* __restrict__ Wf,
                                            const float* __restrict__ bf,
                                            const float* __restrict__ Wp,
                                            const float* __restrict__ bp,
                                            float* __restrict__ out)
{
    __shared__ float red[4][64];
    __shared__ float cm[64];
    __shared__ float ft[64];
    int t  = threadIdx.x;
    int ch = t & 63;
    int q  = t >> 6;                     // 0..3
    float m = 0.f;                       // relu outputs are >= 0
    for (int b = q; b < NBC; b += 4) m = fmaxf(m, pmax[b * 64 + ch]);
    red[q][ch] = m;
    __syncthreads();
    if (t < 64) {
        cm[t] = fmaxf(fmaxf(red[0][t], red[1][t]), fmaxf(red[2][t], red[3][t]));
    }
    __syncthreads();
    if (t < 64) {
        float s = bf[t];
#pragma unroll
        for (int c = 0; c < 64; ++c) s = fmaf(Wf[t*64 + c], cm[c], s);
        float f = fmaxf(s, 0.f);
        ft[t] = f;
        out[t] = f;
    }
    __syncthreads();
    if (t == 0) {
        float z = bp[0];
#pragma unroll
        for (int c = 0; c < 64; ++c) z = fmaf(Wp[c], ft[c], z);
        out[64] = 1.f / (1.f + expf(-z));
    }
}

// ---------------------------------------------------------------------------
extern "C" void kernel_launch(void* const* d_in, const int* in_sizes, int n_in,
                              void* d_out, int out_size, void* d_ws, size_t ws_size,
                              hipStream_t stream)
{
    const float* image   = (const float*)d_in[0];
    const float* corners = (const float*)d_in[1];
    const float* W0      = (const float*)d_in[2];
    const float* b0      = (const float*)d_in[3];
    const float* W1      = (const float*)d_in[4];
    const float* b1      = (const float*)d_in[5];
    const float* W2      = (const float*)d_in[6];
    const float* b2      = (const float*)d_in[7];
    const float* Wf      = (const float*)d_in[8];
    const float* bf      = (const float*)d_in[9];
    const float* Wp      = (const float*)d_in[10];
    const float* bp      = (const float*)d_in[11];
    float* out = (float*)d_out;

    // workspace layout (256B-aligned), ~21.5 MB used
    char* w = (char*)d_ws;
    double* el2loc  = (double*)(w);                  //   262144 B
    double* partial = (double*)(w + 262144);         //     1024 B
    float*  pmax    = (float*) (w + 263168);         //    34048 B
    float*  Wt      = (float*) (w + 297216);         //   147456 B
    float*  imgT    = (float*) (w + 444672);         // 16777216 B
    float*  Y0      = (float*) (w + 17221888);       //  4210688 B -> 21432576

    prep4_k  <<<P4_GRID, 256, 0, stream>>>(corners, W0, W1, W2, image,
                                           el2loc, partial, Wt, imgT);
    convA4_k <<<256, 256, 0, stream>>>(corners, el2loc, partial, imgT, Wt, b0, Y0);
    convBC_k <<<NBC, 256, 0, stream>>>(Y0, Wt + 12288, b1, Wt + 24576, b2, pmax);
    fc_k     <<<1, 256, 0, stream>>>(pmax, Wf, bf, Wp, bp, out);
}